// Round 2
// baseline (1992.602 us; speedup 1.0000x reference)
//
#include <hip/hip_runtime.h>
#include <hip/hip_bf16.h>

// Problem constants (fixed by reference)
#define BN 16
#define CC 64
#define HH 128
#define WW 128
#define HW 16384
#define C3 192
#define NHEADS 8

// NOTE: launcher processes batches in 2 groups of 8 to keep workspace at
// ~172 MB (round-1 crash attributed to 344 MB ws overflow). All kernels
// take per-group base pointers; b = 0..7 within a group.

// ---------------------------------------------------------------------------
// K1: qkv 1x1 conv, one 64-output-channel chunk.
// block = 256 threads covering 256 pixels x 64 out-channels.
// thread = 2 pixels x 32 out-channels. Weights staged LDS as [c][o].
// ---------------------------------------------------------------------------
__global__ __launch_bounds__(256) void k_qkv1(const float* __restrict__ y,
                                              const float* __restrict__ w_qkv,
                                              float* __restrict__ out, int chunk) {
    __shared__ float ws[64 * 64];  // [c][o]
    int tid = threadIdx.x;
    for (int i = tid; i < 4096; i += 256) {
        int c = i >> 6, o = i & 63;
        ws[i] = w_qkv[(chunk * 64 + o) * 64 + c];
    }
    __syncthreads();
    int bid = blockIdx.x;           // 8 * (HW/256) = 512
    int b = bid >> 6;
    int ptile = bid & 63;
    int pxg = tid & 127;            // 128 pixel-pairs
    int osub = tid >> 7;            // 0..1 -> o base osub*32
    int p0 = ptile * 256 + pxg * 2;
    const float* yb = y + (size_t)b * CC * HW + p0;
    float acc0[32];
    float acc1[32];
#pragma unroll
    for (int o = 0; o < 32; ++o) { acc0[o] = 0.f; acc1[o] = 0.f; }
    for (int c = 0; c < 64; ++c) {
        float2 yv = *(const float2*)(yb + (size_t)c * HW);
        const float* wr = &ws[c * 64 + osub * 32];
#pragma unroll
        for (int o = 0; o < 32; ++o) {
            float w = wr[o];
            acc0[o] = fmaf(w, yv.x, acc0[o]);
            acc1[o] = fmaf(w, yv.y, acc1[o]);
        }
    }
    float* ob = out + (size_t)b * 64 * HW + (size_t)(osub * 32) * HW + p0;
#pragma unroll
    for (int o = 0; o < 32; ++o) {
        *(float2*)(ob + (size_t)o * HW) = make_float2(acc0[o], acc1[o]);
    }
}

// ---------------------------------------------------------------------------
// K2: depthwise 3x3 (pad 1) on one 64-channel chunk. thread = 2 horiz pixels.
// in: temp [b][64][HW]; out: qkv buffer at channel offset chunk*64.
// ---------------------------------------------------------------------------
__global__ __launch_bounds__(256) void k_dw(const float* __restrict__ in,
                                            const float* __restrict__ w_dw,
                                            float* __restrict__ out, int chunk) {
    int bid = blockIdx.x;           // 8*64*32 = 16384
    int tid = threadIdx.x;
    int b = bid >> 11;
    int rem = bid & 2047;
    int ch = rem >> 5;
    int tile = rem & 31;
    int pp = tile * 512 + tid * 2;
    int py = pp >> 7, px = pp & 127;
    const float* ib = in + ((size_t)b * 64 + ch) * HW;
    const float* wr = w_dw + (chunk * 64 + ch) * 9;
    float w[9];
#pragma unroll
    for (int i = 0; i < 9; ++i) w[i] = wr[i];
    float a0 = 0.f, a1 = 0.f;
#pragma unroll
    for (int ky = 0; ky < 3; ++ky) {
        int yy = py + ky - 1;
        bool yok = (unsigned)yy < 128u;
#pragma unroll
        for (int kx = 0; kx < 4; ++kx) {
            int xx = px + kx - 1;
            bool ok = yok && ((unsigned)xx < 128u);
            float v = ok ? ib[yy * 128 + xx] : 0.f;
            if (kx < 3) a0 = fmaf(w[ky * 3 + kx], v, a0);
            if (kx > 0) a1 = fmaf(w[ky * 3 + kx - 1], v, a1);
        }
    }
    *(float2*)(out + ((size_t)b * C3 + chunk * 64 + ch) * HW + pp) = make_float2(a0, a1);
}

// ---------------------------------------------------------------------------
// K3: dynamic-kernel fc branch.
// f_conv[b, e*9+o, n] = b_fc[o] + sum_g w_fc[o,g] * qkv_flat[b, n*192 + g*8 + e]
// thread = one (n, e) pair. Each qkv element is read exactly once.
// ---------------------------------------------------------------------------
__global__ __launch_bounds__(256) void k_fc(const float* __restrict__ qkv,
                                            const float* __restrict__ w_fc,
                                            const float* __restrict__ b_fc,
                                            float* __restrict__ fconv) {
    __shared__ float wf[216];
    __shared__ float bf[9];
    int tid = threadIdx.x;
    if (tid < 216) wf[tid] = w_fc[tid];
    if (tid < 9) bf[tid] = b_fc[tid];
    __syncthreads();
    int bid = blockIdx.x;            // 8*512 = 4096
    int b = bid >> 9;
    int rem = bid & 511;             // 32 n per block
    int n = rem * 32 + (tid >> 3);
    int e = tid & 7;
    const float* x = qkv + (size_t)b * C3 * HW + (size_t)n * 192 + e;
    float xe[24];
#pragma unroll
    for (int g = 0; g < 24; ++g) xe[g] = x[g * 8];
    float* ob = fconv + (size_t)b * 72 * HW + n;
#pragma unroll
    for (int o = 0; o < 9; ++o) {
        float acc = bf[o];
#pragma unroll
        for (int g = 0; g < 24; ++g) acc = fmaf(wf[o * 24 + g], xe[g], acc);
        ob[(size_t)(e * 9 + o) * HW] = acc;
    }
}

// ---------------------------------------------------------------------------
// K4: grouped conv 72->64 (groups=8), 3x3 pad 1, + bias. thread = 2 pixels.
// ---------------------------------------------------------------------------
__global__ __launch_bounds__(256) void k_gconv(const float* __restrict__ fconv,
                                               const float* __restrict__ w_dep,
                                               const float* __restrict__ b_dep,
                                               float* __restrict__ outO) {
    int bid = blockIdx.x;          // 8*64*32 = 16384
    int tid = threadIdx.x;
    int b = bid >> 11;
    int rem = bid & 2047;
    int oc = rem >> 5;
    int tile = rem & 31;
    int pp = tile * 512 + tid * 2;
    int py = pp >> 7, px = pp & 127;
    int g0 = oc >> 3;
    const float* wr = w_dep + oc * 81;
    float bias = b_dep[oc];
    float a0 = bias, a1 = bias;
    const float* ibase = fconv + ((size_t)b * 72 + g0 * 9) * HW;
    for (int ic = 0; ic < 9; ++ic) {
        const float* ib = ibase + (size_t)ic * HW;
        const float* wi = wr + ic * 9;
#pragma unroll
        for (int ky = 0; ky < 3; ++ky) {
            int yy = py + ky - 1;
            bool yok = (unsigned)yy < 128u;
#pragma unroll
            for (int kx = 0; kx < 4; ++kx) {
                int xx = px + kx - 1;
                bool ok = yok && ((unsigned)xx < 128u);
                float v = ok ? ib[yy * 128 + xx] : 0.f;
                if (kx < 3) a0 = fmaf(wi[ky * 3 + kx], v, a0);
                if (kx > 0) a1 = fmaf(wi[ky * 3 + kx - 1], v, a1);
            }
        }
    }
    *(float2*)(outO + ((size_t)b * 64 + oc) * HW + pp) = make_float2(a0, a1);
}

// ---------------------------------------------------------------------------
// K5a: inverse L2 norms of q,k channels (qkv channels 0..127 per batch)
// ---------------------------------------------------------------------------
__global__ __launch_bounds__(256) void k_norms(const float* __restrict__ qkv,
                                               float* __restrict__ norms) {
    __shared__ float red[4];
    int bid = blockIdx.x;  // 8*128 = 1024
    int b = bid >> 7, ch = bid & 127;
    const float* p = qkv + ((size_t)b * C3 + ch) * HW;
    float s = 0.f;
    for (int i = threadIdx.x; i < HW; i += 256) {
        float v = p[i];
        s = fmaf(v, v, s);
    }
#pragma unroll
    for (int off = 32; off; off >>= 1) s += __shfl_down(s, off, 64);
    int lane = threadIdx.x & 63, wv = threadIdx.x >> 6;
    if (lane == 0) red[wv] = s;
    __syncthreads();
    if (threadIdx.x == 0) {
        float t = red[0] + red[1] + red[2] + red[3];
        norms[bid] = 1.f / fmaxf(sqrtf(t), 1e-12f);
    }
}

// ---------------------------------------------------------------------------
// K5b: attention matrix: one block per (b, h, c) row; softmax over d.
// ---------------------------------------------------------------------------
__global__ __launch_bounds__(256) void k_attn(const float* __restrict__ qkv,
                                              const float* __restrict__ norms,
                                              const float* __restrict__ temperature,
                                              float* __restrict__ attn) {
    __shared__ float red[4][8];
    __shared__ float lg[8];
    int bid = blockIdx.x;  // 8*8*8 = 512
    int b = bid >> 6, h = (bid >> 3) & 7, c = bid & 7;
    const float* Q = qkv + ((size_t)b * C3 + h * 8 + c) * HW;
    const float* K = qkv + ((size_t)b * C3 + 64 + h * 8) * HW;
    float acc[8];
#pragma unroll
    for (int d = 0; d < 8; ++d) acc[d] = 0.f;
    for (int i = threadIdx.x; i < HW; i += 256) {
        float qv = Q[i];
#pragma unroll
        for (int d = 0; d < 8; ++d) acc[d] = fmaf(qv, K[(size_t)d * HW + i], acc[d]);
    }
#pragma unroll
    for (int d = 0; d < 8; ++d) {
#pragma unroll
        for (int off = 32; off; off >>= 1) acc[d] += __shfl_down(acc[d], off, 64);
    }
    int lane = threadIdx.x & 63, wv = threadIdx.x >> 6;
    if (lane == 0) {
#pragma unroll
        for (int d = 0; d < 8; ++d) red[wv][d] = acc[d];
    }
    __syncthreads();
    if (threadIdx.x < 8) {
        int d = threadIdx.x;
        float s = red[0][d] + red[1][d] + red[2][d] + red[3][d];
        float invq = norms[b * 128 + h * 8 + c];
        float invk = norms[b * 128 + 64 + h * 8 + d];
        lg[d] = s * invq * invk * temperature[h];
    }
    __syncthreads();
    if (threadIdx.x == 0) {
        float m = lg[0];
#pragma unroll
        for (int d = 1; d < 8; ++d) m = fmaxf(m, lg[d]);
        float ssum = 0.f, ex[8];
#pragma unroll
        for (int d = 0; d < 8; ++d) { ex[d] = expf(lg[d] - m); ssum += ex[d]; }
        float inv = 1.f / ssum;
#pragma unroll
        for (int d = 0; d < 8; ++d) attn[bid * 8 + d] = ex[d] * inv;
    }
}

// ---------------------------------------------------------------------------
// K5c: out = attn.V per head, then 1x1 proj, added in-place into outO.
// thread = 1 pixel, 64 channels.
// ---------------------------------------------------------------------------
__global__ __launch_bounds__(256) void k_av_proj(const float* __restrict__ qkv,
                                                 const float* __restrict__ attn,
                                                 const float* __restrict__ w_proj,
                                                 float* __restrict__ outO) {
    __shared__ float at[512];
    __shared__ float wp[4096];  // [c][o]
    int tid = threadIdx.x;
    int bid = blockIdx.x;  // 8*64 = 512
    int b = bid >> 6, tile = bid & 63;
    for (int i = tid; i < 512; i += 256) at[i] = attn[b * 512 + i];
    for (int i = tid; i < 4096; i += 256) {
        int c = i >> 6, o = i & 63;
        wp[i] = w_proj[o * 64 + c];
    }
    __syncthreads();
    int p = tile * 256 + tid;
    const float* vb = qkv + ((size_t)b * C3 + 128) * HW + p;
    float av[64];
#pragma unroll
    for (int h = 0; h < 8; ++h) {
        float vv[8];
#pragma unroll
        for (int d = 0; d < 8; ++d) vv[d] = vb[(size_t)(h * 8 + d) * HW];
#pragma unroll
        for (int ci = 0; ci < 8; ++ci) {
            float s = 0.f;
#pragma unroll
            for (int d = 0; d < 8; ++d) s = fmaf(at[(h * 8 + ci) * 8 + d], vv[d], s);
            av[h * 8 + ci] = s;
        }
    }
    float* ob = outO + (size_t)b * 64 * HW + p;
    float acc[64];
#pragma unroll
    for (int o = 0; o < 64; ++o) acc[o] = ob[(size_t)o * HW];
    for (int c = 0; c < 64; ++c) {
        float a = av[c];
        const float* wr = &wp[c * 64];
#pragma unroll
        for (int o = 0; o < 64; ++o) acc[o] = fmaf(wr[o], a, acc[o]);
    }
#pragma unroll
    for (int o = 0; o < 64; ++o) ob[(size_t)o * HW] = acc[o];
}

// ---------------------------------------------------------------------------
// K6: fuse 3x3 conv 64->64 + BN + residual ReLU.
// block: 16x16 pixel tile x 16 out-channels. thread = 2x2 pixels x 4 o.
// weights staged LDS as [c][k][o16] for b128 broadcast reads.
// ---------------------------------------------------------------------------
__global__ __launch_bounds__(256) void k_fuse(const float* __restrict__ outO,
                                              const float* __restrict__ w_fuse,
                                              const float* __restrict__ bn_gamma,
                                              const float* __restrict__ bn_beta,
                                              const float* __restrict__ bn_mean,
                                              const float* __restrict__ bn_var,
                                              const float* __restrict__ y,
                                              float* __restrict__ dout) {
    __shared__ float wl[64 * 9 * 16];  // 36864 B, [c][k][o16]
    int tid = threadIdx.x;
    int bid = blockIdx.x;  // 8 * 4 * 64 = 2048
    int b = bid >> 8;
    int rem = bid & 255;
    int ob16 = rem >> 6;          // o block 0..3 (16 o each)
    int tile = rem & 63;
    int ty0 = (tile >> 3) * 16, tx0 = (tile & 7) * 16;
    for (int i = tid; i < 9216; i += 256) {
        int c = i / 144;
        int r = i % 144;
        int k = r >> 4;
        int o = r & 15;
        wl[i] = w_fuse[((size_t)(ob16 * 16 + o) * 64 + c) * 9 + k];
    }
    __syncthreads();
    int osub = tid >> 6;          // 0..3 -> 4 o each
    int pxg = tid & 63;
    int pgy = pxg >> 3, pgx = pxg & 7;
    int py0 = ty0 + pgy * 2, px0 = tx0 + pgx * 2;
    const float* ib = outO + (size_t)b * 64 * HW;
    float acc[4][4];  // [px][o]
#pragma unroll
    for (int d = 0; d < 4; ++d)
#pragma unroll
        for (int o = 0; o < 4; ++o) acc[d][o] = 0.f;
    for (int c = 0; c < 64; ++c) {
        float nb[4][4];
        const float* icp = ib + (size_t)c * HW;
#pragma unroll
        for (int r = 0; r < 4; ++r) {
            int yy = py0 + r - 1;
            bool yok = (unsigned)yy < 128u;
#pragma unroll
            for (int q = 0; q < 4; ++q) {
                int xx = px0 + q - 1;
                nb[r][q] = (yok && (unsigned)xx < 128u) ? icp[yy * 128 + xx] : 0.f;
            }
        }
        const float* wc = &wl[c * 144 + osub * 4];
#pragma unroll
        for (int ky = 0; ky < 3; ++ky) {
#pragma unroll
            for (int kx = 0; kx < 3; ++kx) {
                const float* wk = wc + (ky * 3 + kx) * 16;
#pragma unroll
                for (int o = 0; o < 4; ++o) {
                    float w = wk[o];
                    acc[0][o] = fmaf(w, nb[ky][kx], acc[0][o]);
                    acc[1][o] = fmaf(w, nb[ky][kx + 1], acc[1][o]);
                    acc[2][o] = fmaf(w, nb[ky + 1][kx], acc[2][o]);
                    acc[3][o] = fmaf(w, nb[ky + 1][kx + 1], acc[3][o]);
                }
            }
        }
    }
#pragma unroll
    for (int o = 0; o < 4; ++o) {
        int og = ob16 * 16 + osub * 4 + o;
        float sc = bn_gamma[og] * rsqrtf(bn_var[og] + 1e-5f);
        float mu = bn_mean[og], bt = bn_beta[og];
#pragma unroll
        for (int d = 0; d < 4; ++d) {
            int pyy = py0 + (d >> 1), pxx = px0 + (d & 1);
            size_t idx = ((size_t)b * 64 + og) * HW + pyy * 128 + pxx;
            float v = (acc[d][o] - mu) * sc + bt + y[idx];
            dout[idx] = fmaxf(v, 0.f);
        }
    }
}

// ---------------------------------------------------------------------------
extern "C" void kernel_launch(void* const* d_in, const int* in_sizes, int n_in,
                              void* d_out, int out_size, void* d_ws, size_t ws_size,
                              hipStream_t stream) {
    const float* y           = (const float*)d_in[0];
    const float* w_qkv       = (const float*)d_in[1];
    const float* w_dw        = (const float*)d_in[2];
    const float* w_proj      = (const float*)d_in[3];
    const float* w_fc        = (const float*)d_in[4];
    const float* b_fc        = (const float*)d_in[5];
    const float* w_dep       = (const float*)d_in[6];
    const float* b_dep       = (const float*)d_in[7];
    const float* temperature = (const float*)d_in[8];
    const float* w_fuse      = (const float*)d_in[9];
    const float* bn_gamma    = (const float*)d_in[10];
    const float* bn_beta     = (const float*)d_in[11];
    const float* bn_mean     = (const float*)d_in[12];
    const float* bn_var      = (const float*)d_in[13];
    float* out = (float*)d_out;

    // Per-group scratch (8 batches/group), total ~172 MB:
    float* ws    = (float*)d_ws;
    float* qkvB  = ws;               // [8][192][16384] = 25,165,824 f
    float* bufT  = ws + 25165824;    // qkv1 temp (8.4M f) / fconv (9.4M f)
    float* bufO  = ws + 34603008;    // out_conv -> output, 8,388,608 f
    float* norms = ws + 42991616;    // 1024 f
    float* attn  = ws + 42992640;    // 4096 f
    (void)in_sizes; (void)n_in; (void)out_size; (void)ws_size;

    for (int g = 0; g < 2; ++g) {
        const float* yg = y + (size_t)g * 8 * CC * HW;
        float* outg = out + (size_t)g * 8 * CC * HW;
        for (int chunk = 0; chunk < 3; ++chunk) {
            k_qkv1<<<512, 256, 0, stream>>>(yg, w_qkv, bufT, chunk);
            k_dw<<<16384, 256, 0, stream>>>(bufT, w_dw, qkvB, chunk);
        }
        k_fc<<<4096, 256, 0, stream>>>(qkvB, w_fc, b_fc, bufT);
        k_gconv<<<16384, 256, 0, stream>>>(bufT, w_dep, b_dep, bufO);
        k_norms<<<1024, 256, 0, stream>>>(qkvB, norms);
        k_attn<<<512, 256, 0, stream>>>(qkvB, norms, temperature, attn);
        k_av_proj<<<512, 256, 0, stream>>>(qkvB, attn, w_proj, bufO);
        k_fuse<<<2048, 256, 0, stream>>>(bufO, w_fuse, bn_gamma, bn_beta,
                                         bn_mean, bn_var, yg, outg);
    }
}

// Round 4
// 1045.001 us; speedup vs baseline: 1.9068x; 1.9068x over previous
//
#include <hip/hip_runtime.h>
#include <hip/hip_bf16.h>

// Problem constants (fixed by reference)
#define BN 16
#define CC 64
#define HH 128
#define WW 128
#define HW 16384
#define C3 192
#define NHEADS 8

// NOTE: launcher processes batches in 2 groups of 8 (workspace ~172 MB).

// ---------------------------------------------------------------------------
// K1: qkv 1x1 conv, one 64-output-channel chunk.
// ---------------------------------------------------------------------------
__global__ __launch_bounds__(256) void k_qkv1(const float* __restrict__ y,
                                              const float* __restrict__ w_qkv,
                                              float* __restrict__ out, int chunk) {
    __shared__ float ws[64 * 64];  // [c][o]
    int tid = threadIdx.x;
    for (int i = tid; i < 4096; i += 256) {
        int c = i >> 6, o = i & 63;
        ws[i] = w_qkv[(chunk * 64 + o) * 64 + c];
    }
    __syncthreads();
    int bid = blockIdx.x;           // 8 * (HW/256) = 512
    int b = bid >> 6;
    int ptile = bid & 63;
    int pxg = tid & 127;            // 128 pixel-pairs
    int osub = tid >> 7;            // 0..1 -> o base osub*32
    int p0 = ptile * 256 + pxg * 2;
    const float* yb = y + (size_t)b * CC * HW + p0;
    float acc0[32];
    float acc1[32];
#pragma unroll
    for (int o = 0; o < 32; ++o) { acc0[o] = 0.f; acc1[o] = 0.f; }
    for (int c = 0; c < 64; ++c) {
        float2 yv = *(const float2*)(yb + (size_t)c * HW);
        const float* wr = &ws[c * 64 + osub * 32];
#pragma unroll
        for (int o = 0; o < 32; ++o) {
            float w = wr[o];
            acc0[o] = fmaf(w, yv.x, acc0[o]);
            acc1[o] = fmaf(w, yv.y, acc1[o]);
        }
    }
    float* ob = out + (size_t)b * 64 * HW + (size_t)(osub * 32) * HW + p0;
#pragma unroll
    for (int o = 0; o < 32; ++o) {
        *(float2*)(ob + (size_t)o * HW) = make_float2(acc0[o], acc1[o]);
    }
}

// ---------------------------------------------------------------------------
// K2: depthwise 3x3 (pad 1) on one 64-channel chunk. thread = 2 horiz pixels.
// ---------------------------------------------------------------------------
__global__ __launch_bounds__(256) void k_dw(const float* __restrict__ in,
                                            const float* __restrict__ w_dw,
                                            float* __restrict__ out, int chunk) {
    int bid = blockIdx.x;           // 8*64*32 = 16384
    int tid = threadIdx.x;
    int b = bid >> 11;
    int rem = bid & 2047;
    int ch = rem >> 5;
    int tile = rem & 31;
    int pp = tile * 512 + tid * 2;
    int py = pp >> 7, px = pp & 127;
    const float* ib = in + ((size_t)b * 64 + ch) * HW;
    const float* wr = w_dw + (chunk * 64 + ch) * 9;
    float w[9];
#pragma unroll
    for (int i = 0; i < 9; ++i) w[i] = wr[i];
    float a0 = 0.f, a1 = 0.f;
#pragma unroll
    for (int ky = 0; ky < 3; ++ky) {
        int yy = py + ky - 1;
        bool yok = (unsigned)yy < 128u;
#pragma unroll
        for (int kx = 0; kx < 4; ++kx) {
            int xx = px + kx - 1;
            bool ok = yok && ((unsigned)xx < 128u);
            float v = ok ? ib[yy * 128 + xx] : 0.f;
            if (kx < 3) a0 = fmaf(w[ky * 3 + kx], v, a0);
            if (kx > 0) a1 = fmaf(w[ky * 3 + kx - 1], v, a1);
        }
    }
    *(float2*)(out + ((size_t)b * C3 + chunk * 64 + ch) * HW + pp) = make_float2(a0, a1);
}

// ---------------------------------------------------------------------------
// K3: dynamic-kernel fc branch.
// f_conv[b, e*9+o, n] = b_fc[o] + sum_g w_fc[o,g] * qkv_flat[b, n*192 + g*8 + e]
// ---------------------------------------------------------------------------
__global__ __launch_bounds__(256) void k_fc(const float* __restrict__ qkv,
                                            const float* __restrict__ w_fc,
                                            const float* __restrict__ b_fc,
                                            float* __restrict__ fconv) {
    __shared__ float wf[216];
    __shared__ float bf[9];
    int tid = threadIdx.x;
    if (tid < 216) wf[tid] = w_fc[tid];
    if (tid < 9) bf[tid] = b_fc[tid];
    __syncthreads();
    int bid = blockIdx.x;            // 8*512 = 4096
    int b = bid >> 9;
    int rem = bid & 511;             // 32 n per block
    int n = rem * 32 + (tid >> 3);
    int e = tid & 7;
    const float* x = qkv + (size_t)b * C3 * HW + (size_t)n * 192 + e;
    float xe[24];
#pragma unroll
    for (int g = 0; g < 24; ++g) xe[g] = x[g * 8];
    float* ob = fconv + (size_t)b * 72 * HW + n;
#pragma unroll
    for (int o = 0; o < 9; ++o) {
        float acc = bf[o];
#pragma unroll
        for (int g = 0; g < 24; ++g) acc = fmaf(wf[o * 24 + g], xe[g], acc);
        ob[(size_t)(e * 9 + o) * HW] = acc;
    }
}

// ---------------------------------------------------------------------------
// K4: grouped conv 72->64 (groups=8), 3x3 pad 1, + bias. (REWRITTEN: LDS-tiled)
// Block = 16x16 pixel tile x one conv group (8 oc, 9 ic). Stage 9 input
// channels [18][20] + 648 weights in ~15 KB LDS. Thread = 1 px x 8 oc.
// ---------------------------------------------------------------------------
#define GST 20
__global__ __launch_bounds__(256) void k_gconv(const float* __restrict__ fconv,
                                               const float* __restrict__ w_dep,
                                               const float* __restrict__ b_dep,
                                               float* __restrict__ outO) {
    __shared__ __align__(16) float sm_in[9 * 18 * GST];  // 12.7 KB
    __shared__ __align__(16) float sm_w[81 * 8];         // [ic*9+kk][o]
    __shared__ float sm_b[8];
    int tid = threadIdx.x;
    int bid = blockIdx.x;          // 8 * 8 * 64 = 4096
    int b = bid >> 9;
    int rem = bid & 511;
    int grp = rem >> 6;            // conv group 0..7
    int tile = rem & 63;
    int ty0 = (tile >> 3) * 16, tx0 = (tile & 7) * 16;
    const float* ibase = fconv + ((size_t)b * 72 + grp * 9) * HW;
    for (int i = tid; i < 9 * 324; i += 256) {
        int c = i / 324;
        int r2 = i - c * 324;
        int r = r2 / 18;
        int q = r2 - r * 18;
        int yy = ty0 + r - 1, xx = tx0 + q - 1;
        sm_in[c * (18 * GST) + r * GST + q] =
            ((unsigned)yy < 128u && (unsigned)xx < 128u)
                ? ibase[(size_t)c * HW + yy * 128 + xx] : 0.f;
    }
    for (int i = tid; i < 648; i += 256) {
        int o = i & 7;
        int ik = i >> 3;           // ic*9+kk, 0..80
        sm_w[i] = w_dep[(size_t)(grp * 8 + o) * 81 + ik];
    }
    if (tid < 8) sm_b[tid] = b_dep[grp * 8 + tid];
    __syncthreads();
    int row = tid >> 4, col = tid & 15;
    float acc[8];
#pragma unroll
    for (int o = 0; o < 8; ++o) acc[o] = sm_b[o];
#pragma unroll
    for (int ic = 0; ic < 9; ++ic) {
        float nb[3][3];
        const float* sc = &sm_in[ic * (18 * GST) + row * GST + col];
#pragma unroll
        for (int r = 0; r < 3; ++r)
#pragma unroll
            for (int q = 0; q < 3; ++q) nb[r][q] = sc[r * GST + q];
        const float* wp = &sm_w[ic * 72];
#pragma unroll
        for (int k = 0; k < 9; ++k) {
            float4 w0 = *(const float4*)(wp + k * 8);
            float4 w1 = *(const float4*)(wp + k * 8 + 4);
            float v = nb[k / 3][k % 3];
            acc[0] = fmaf(w0.x, v, acc[0]);
            acc[1] = fmaf(w0.y, v, acc[1]);
            acc[2] = fmaf(w0.z, v, acc[2]);
            acc[3] = fmaf(w0.w, v, acc[3]);
            acc[4] = fmaf(w1.x, v, acc[4]);
            acc[5] = fmaf(w1.y, v, acc[5]);
            acc[6] = fmaf(w1.z, v, acc[6]);
            acc[7] = fmaf(w1.w, v, acc[7]);
        }
    }
    float* ob = outO + ((size_t)b * 64 + grp * 8) * HW + (ty0 + row) * 128 + tx0 + col;
#pragma unroll
    for (int o = 0; o < 8; ++o) ob[(size_t)o * HW] = acc[o];
}

// ---------------------------------------------------------------------------
// K5b: attention matrix, with Q/K L2-norms fused in (k_norms eliminated).
// One block per (b,h): streams the 16 relevant channels once, accumulates
// 64 logits + 16 sum-of-squares, reduces in-block, softmax over d.
// ---------------------------------------------------------------------------
__global__ __launch_bounds__(256) void k_attn(const float* __restrict__ qkv,
                                              const float* __restrict__ temperature,
                                              float* __restrict__ attn) {
    __shared__ float red[4][64];
    __shared__ float redq[4][8];
    __shared__ float redk[4][8];
    __shared__ float sm_inv[16];
    __shared__ float lg[64];
    int bid = blockIdx.x;  // 8*8 = 64
    int b = bid >> 3, h = bid & 7;
    int tid = threadIdx.x;
    const float* Q = qkv + ((size_t)b * C3 + h * 8) * HW;
    const float* K = Q + (size_t)64 * HW;
    float acc[64], qs[8], ks[8];
#pragma unroll
    for (int j = 0; j < 64; ++j) acc[j] = 0.f;
#pragma unroll
    for (int d = 0; d < 8; ++d) { qs[d] = 0.f; ks[d] = 0.f; }
    for (int i = tid; i < HW; i += 256) {
        float qv[8], kv[8];
#pragma unroll
        for (int d = 0; d < 8; ++d) {
            qv[d] = Q[(size_t)d * HW + i];
            kv[d] = K[(size_t)d * HW + i];
        }
#pragma unroll
        for (int d = 0; d < 8; ++d) {
            qs[d] = fmaf(qv[d], qv[d], qs[d]);
            ks[d] = fmaf(kv[d], kv[d], ks[d]);
        }
#pragma unroll
        for (int c = 0; c < 8; ++c)
#pragma unroll
            for (int d = 0; d < 8; ++d)
                acc[c * 8 + d] = fmaf(qv[c], kv[d], acc[c * 8 + d]);
    }
#pragma unroll
    for (int j = 0; j < 64; ++j) {
#pragma unroll
        for (int off = 32; off; off >>= 1) acc[j] += __shfl_down(acc[j], off, 64);
    }
#pragma unroll
    for (int d = 0; d < 8; ++d) {
#pragma unroll
        for (int off = 32; off; off >>= 1) {
            qs[d] += __shfl_down(qs[d], off, 64);
            ks[d] += __shfl_down(ks[d], off, 64);
        }
    }
    int lane = tid & 63, wv = tid >> 6;
    if (lane == 0) {
#pragma unroll
        for (int j = 0; j < 64; ++j) red[wv][j] = acc[j];
#pragma unroll
        for (int d = 0; d < 8; ++d) { redq[wv][d] = qs[d]; redk[wv][d] = ks[d]; }
    }
    __syncthreads();
    if (tid < 16) {
        int d = tid & 7;
        float s = (tid < 8) ? (redq[0][d] + redq[1][d] + redq[2][d] + redq[3][d])
                            : (redk[0][d] + redk[1][d] + redk[2][d] + redk[3][d]);
        sm_inv[tid] = 1.f / fmaxf(sqrtf(s), 1e-12f);
    }
    __syncthreads();
    if (tid < 64) {
        float s = red[0][tid] + red[1][tid] + red[2][tid] + red[3][tid];
        int c = tid >> 3, d = tid & 7;
        lg[tid] = s * sm_inv[c] * sm_inv[8 + d] * temperature[h];
    }
    __syncthreads();
    if (tid < 8) {
        int c = tid;
        float m = lg[c * 8];
#pragma unroll
        for (int d = 1; d < 8; ++d) m = fmaxf(m, lg[c * 8 + d]);
        float ssum = 0.f, ex[8];
#pragma unroll
        for (int d = 0; d < 8; ++d) { ex[d] = expf(lg[c * 8 + d] - m); ssum += ex[d]; }
        float inv = 1.f / ssum;
#pragma unroll
        for (int d = 0; d < 8; ++d)
            attn[((size_t)(b * 8 + h) * 8 + c) * 8 + d] = ex[d] * inv;
    }
}

// ---------------------------------------------------------------------------
// K5c: out = attn.V per head, then 1x1 proj, added in-place into outO.
// ---------------------------------------------------------------------------
__global__ __launch_bounds__(256) void k_av_proj(const float* __restrict__ qkv,
                                                 const float* __restrict__ attn,
                                                 const float* __restrict__ w_proj,
                                                 float* __restrict__ outO) {
    __shared__ float at[512];
    __shared__ float wp[4096];  // [c][o]
    int tid = threadIdx.x;
    int bid = blockIdx.x;  // 8*64 = 512
    int b = bid >> 6, tile = bid & 63;
    for (int i = tid; i < 512; i += 256) at[i] = attn[b * 512 + i];
    for (int i = tid; i < 4096; i += 256) {
        int c = i >> 6, o = i & 63;
        wp[i] = w_proj[o * 64 + c];
    }
    __syncthreads();
    int p = tile * 256 + tid;
    const float* vb = qkv + ((size_t)b * C3 + 128) * HW + p;
    float av[64];
#pragma unroll
    for (int h = 0; h < 8; ++h) {
        float vv[8];
#pragma unroll
        for (int d = 0; d < 8; ++d) vv[d] = vb[(size_t)(h * 8 + d) * HW];
#pragma unroll
        for (int ci = 0; ci < 8; ++ci) {
            float s = 0.f;
#pragma unroll
            for (int d = 0; d < 8; ++d) s = fmaf(at[(h * 8 + ci) * 8 + d], vv[d], s);
            av[h * 8 + ci] = s;
        }
    }
    float* ob = outO + (size_t)b * 64 * HW + p;
    float acc[64];
#pragma unroll
    for (int o = 0; o < 64; ++o) acc[o] = ob[(size_t)o * HW];
    for (int c = 0; c < 64; ++c) {
        float a = av[c];
        const float* wr = &wp[c * 64];
#pragma unroll
        for (int o = 0; o < 64; ++o) acc[o] = fmaf(wr[o], a, acc[o]);
    }
#pragma unroll
    for (int o = 0; o < 64; ++o) ob[(size_t)o * HW] = acc[o];
}

// ---------------------------------------------------------------------------
// K6: fuse 3x3 conv 64->64 + BN + residual ReLU.  (LDS-tiled)
// Block: 16x16 pixel tile x ALL 64 out-channels; c looped in 8 chunks of 8.
// Per chunk: stage input 18x18x8 (pad [18][20]) + weights [8][9][64] in LDS.
// Thread = 4 rows x 1 col x 16 o -> 64 acc; 576 FMA per c vs ~54 LDS reads.
// ---------------------------------------------------------------------------
#define ST 20  // padded row stride for input tile
__global__ __launch_bounds__(256) void k_fuse(const float* __restrict__ outO,
                                              const float* __restrict__ w_fuse,
                                              const float* __restrict__ bn_gamma,
                                              const float* __restrict__ bn_beta,
                                              const float* __restrict__ bn_mean,
                                              const float* __restrict__ bn_var,
                                              const float* __restrict__ y,
                                              float* __restrict__ dout) {
    __shared__ __align__(16) float sm_in[8 * 18 * ST];   // 11.25 KB
    __shared__ __align__(16) float sm_w[8 * 9 * 64];     // 18 KB, [c][k][o]
    __shared__ float sm_sc[64];
    __shared__ float sm_sb[64];
    int tid = threadIdx.x;
    int bid = blockIdx.x;          // 8 * 64 = 512
    int b = bid >> 6;
    int tile = bid & 63;
    int ty0 = (tile >> 3) * 16, tx0 = (tile & 7) * 16;

    if (tid < 64) {
        float sc = bn_gamma[tid] * rsqrtf(bn_var[tid] + 1e-5f);
        sm_sc[tid] = sc;
        sm_sb[tid] = bn_beta[tid] - bn_mean[tid] * sc;
    }

    int osub = tid >> 6;           // wave id 0..3 -> o0 = osub*16
    int o0 = osub * 16;
    int lane = tid & 63;
    int col = lane & 15;           // 0..15 (output col within tile)
    int rowg = lane >> 4;          // 0..3  (4 output rows each)
    int r0 = rowg * 4;

    const float* ib = outO + (size_t)b * 64 * HW;
    float acc[4][16];
#pragma unroll
    for (int p = 0; p < 4; ++p)
#pragma unroll
        for (int o = 0; o < 16; ++o) acc[p][o] = 0.f;

    for (int ch = 0; ch < 8; ++ch) {
        int c0 = ch * 8;
        __syncthreads();   // protect LDS from previous iteration's readers
        // stage input 18x18 x 8 channels (zero-padded halo)
        for (int i = tid; i < 8 * 18 * 18; i += 256) {
            int c = i / 324;
            int rem = i - c * 324;
            int r = rem / 18;
            int q = rem - r * 18;
            int yy = ty0 + r - 1;
            int xx = tx0 + q - 1;
            float v = ((unsigned)yy < 128u && (unsigned)xx < 128u)
                          ? ib[(size_t)(c0 + c) * HW + yy * 128 + xx] : 0.f;
            sm_in[c * (18 * ST) + r * ST + q] = v;
        }
        // stage weights [c][k][o]; o innermost -> conflict-free LDS writes
        for (int i = tid; i < 8 * 9 * 64; i += 256) {
            int o = i & 63;
            int kk = (i >> 6) % 9;
            int c = i / 576;
            sm_w[(c * 9 + kk) * 64 + o] = w_fuse[((size_t)o * 64 + (c0 + c)) * 9 + kk];
        }
        __syncthreads();
        for (int cc = 0; cc < 8; ++cc) {
            float nb[6][3];
            const float* sin_c = &sm_in[cc * (18 * ST)];
#pragma unroll
            for (int r = 0; r < 6; ++r)
#pragma unroll
                for (int q = 0; q < 3; ++q)
                    nb[r][q] = sin_c[(r0 + r) * ST + col + q];
            const float* wc = &sm_w[cc * 576 + o0];
#pragma unroll
            for (int k = 0; k < 9; ++k) {
                int ky = k / 3, kx = k % 3;
                float4 w0 = *(const float4*)(wc + k * 64);
                float4 w1 = *(const float4*)(wc + k * 64 + 4);
                float4 w2 = *(const float4*)(wc + k * 64 + 8);
                float4 w3 = *(const float4*)(wc + k * 64 + 12);
#pragma unroll
                for (int p = 0; p < 4; ++p) {
                    float v = nb[p + ky][kx];
                    acc[p][0]  = fmaf(w0.x, v, acc[p][0]);
                    acc[p][1]  = fmaf(w0.y, v, acc[p][1]);
                    acc[p][2]  = fmaf(w0.z, v, acc[p][2]);
                    acc[p][3]  = fmaf(w0.w, v, acc[p][3]);
                    acc[p][4]  = fmaf(w1.x, v, acc[p][4]);
                    acc[p][5]  = fmaf(w1.y, v, acc[p][5]);
                    acc[p][6]  = fmaf(w1.z, v, acc[p][6]);
                    acc[p][7]  = fmaf(w1.w, v, acc[p][7]);
                    acc[p][8]  = fmaf(w2.x, v, acc[p][8]);
                    acc[p][9]  = fmaf(w2.y, v, acc[p][9]);
                    acc[p][10] = fmaf(w2.z, v, acc[p][10]);
                    acc[p][11] = fmaf(w2.w, v, acc[p][11]);
                    acc[p][12] = fmaf(w3.x, v, acc[p][12]);
                    acc[p][13] = fmaf(w3.y, v, acc[p][13]);
                    acc[p][14] = fmaf(w3.z, v, acc[p][14]);
                    acc[p][15] = fmaf(w3.w, v, acc[p][15]);
                }
            }
        }
    }
    // epilogue: BN + residual + ReLU
#pragma unroll
    for (int o = 0; o < 16; ++o) {
        int og = o0 + o;
        float sc = sm_sc[og], sb = sm_sb[og];
#pragma unroll
        for (int p = 0; p < 4; ++p) {
            int pyy = ty0 + r0 + p;
            int pxx = tx0 + col;
            size_t idx = ((size_t)b * 64 + og) * HW + pyy * 128 + pxx;
            float v = acc[p][o] * sc + sb + y[idx];
            dout[idx] = fmaxf(v, 0.f);
        }
    }
}

// ---------------------------------------------------------------------------
extern "C" void kernel_launch(void* const* d_in, const int* in_sizes, int n_in,
                              void* d_out, int out_size, void* d_ws, size_t ws_size,
                              hipStream_t stream) {
    const float* y           = (const float*)d_in[0];
    const float* w_qkv       = (const float*)d_in[1];
    const float* w_dw        = (const float*)d_in[2];
    const float* w_proj      = (const float*)d_in[3];
    const float* w_fc        = (const float*)d_in[4];
    const float* b_fc        = (const float*)d_in[5];
    const float* w_dep       = (const float*)d_in[6];
    const float* b_dep       = (const float*)d_in[7];
    const float* temperature = (const float*)d_in[8];
    const float* w_fuse      = (const float*)d_in[9];
    const float* bn_gamma    = (const float*)d_in[10];
    const float* bn_beta     = (const float*)d_in[11];
    const float* bn_mean     = (const float*)d_in[12];
    const float* bn_var      = (const float*)d_in[13];
    float* out = (float*)d_out;

    // Per-group scratch (8 batches/group), total ~172 MB:
    float* ws    = (float*)d_ws;
    float* qkvB  = ws;               // [8][192][16384] = 25,165,824 f
    float* bufT  = ws + 25165824;    // qkv1 temp (8.4M f) / fconv (9.4M f)
    float* bufO  = ws + 34603008;    // out_conv -> output, 8,388,608 f
    float* attn  = ws + 42992640;    // 4096 f
    (void)in_sizes; (void)n_in; (void)out_size; (void)ws_size;

    for (int g = 0; g < 2; ++g) {
        const float* yg = y + (size_t)g * 8 * CC * HW;
        float* outg = out + (size_t)g * 8 * CC * HW;
        for (int chunk = 0; chunk < 3; ++chunk) {
            k_qkv1<<<512, 256, 0, stream>>>(yg, w_qkv, bufT, chunk);
            k_dw<<<16384, 256, 0, stream>>>(bufT, w_dw, qkvB, chunk);
        }
        k_fc<<<4096, 256, 0, stream>>>(qkvB, w_fc, b_fc, bufT);
        k_gconv<<<4096, 256, 0, stream>>>(bufT, w_dep, b_dep, bufO);
        k_attn<<<64, 256, 0, stream>>>(qkvB, temperature, attn);
        k_av_proj<<<512, 256, 0, stream>>>(qkvB, attn, w_proj, bufO);
        k_fuse<<<512, 256, 0, stream>>>(bufO, w_fuse, bn_gamma, bn_beta,
                                        bn_mean, bn_var, yg, outg);
    }
}